// Round 3
// baseline (169.256 us; speedup 1.0000x reference)
//
#include <hip/hip_runtime.h>
#include <hip/hip_bf16.h>

#define NN 65536
#define EE 524288
#define BB 256
#define LL 64
#define HH 128
#define DD2 256
#define NEF 1024

typedef __attribute__((ext_vector_type(4))) float f32x4;
typedef __attribute__((ext_vector_type(8))) __bf16 bf16x8;

// K1: fused z-path: z_proj (LDS-only) -> Zt/Zb/ZN rows; energy/stress heads;
// plus weight conversions W_nep->Bp, W_nd1->Bp2 (bf16, fragment-permuted
// [K/8][col][8]) with fully coalesced reads and 16B stores.
__global__ __launch_bounds__(256) void k1_prep(
    const float* __restrict__ z, const float* __restrict__ lattice,
    const float* __restrict__ W_lat, const float* __restrict__ b_lat,
    const float* __restrict__ W_en1, const float* __restrict__ b_en1,
    const float* __restrict__ W_en2, const float* __restrict__ b_en2,
    const float* __restrict__ W_st1, const float* __restrict__ b_st1,
    const float* __restrict__ W_st2, const float* __restrict__ b_st2,
    const float* __restrict__ W_nep, const float* __restrict__ W_nd1,
    const float* __restrict__ W_ed1,
    float* __restrict__ Zt, float* __restrict__ Zb, float* __restrict__ ZN,
    __bf16* __restrict__ Bp, __bf16* __restrict__ Bp2,
    float* __restrict__ out_en, float* __restrict__ out_st)
{
  int b = blockIdx.x, t = threadIdx.x;
  if (b < BB) {
    __shared__ float zl[70];
    __shared__ float zp[DD2];
    __shared__ float he[HH];
    __shared__ float hs[HH];
    if (t < LL) zl[t] = z[b*LL + t];
    else if (t < 70) zl[t] = lattice[t - LL];
    __syncthreads();
    {
      float acc = b_lat[t];
      #pragma unroll 4
      for (int k = 0; k < LL; ++k) acc = fmaf(zl[k], W_lat[k*DD2 + t], acc);
      zp[t] = fmaxf(acc, 0.f);
    }
    if (t < HH) {
      float a = b_en1[t];
      for (int k = 0; k < 70; ++k) a = fmaf(zl[k], W_en1[k*HH + t], a);
      he[t] = fmaxf(a, 0.f);
    } else {
      int tt = t - HH;
      float a = b_st1[tt];
      for (int k = 0; k < 70; ++k) a = fmaf(zl[k], W_st1[k*HH + tt], a);
      hs[tt] = fmaxf(a, 0.f);
    }
    __syncthreads();
    if (t < HH) {
      float a = 0.f, n = 0.f;
      #pragma unroll 4
      for (int k = 0; k < DD2; ++k) {
        a = fmaf(zp[k], W_ed1[k*HH + t], a);
        n = fmaf(zp[k], W_nd1[k*HH + t], n);
      }
      Zt[b*HH + t] = a;
      ZN[b*HH + t] = n;
    } else {
      int tt = t - HH;
      float a = 0.f;
      #pragma unroll 4
      for (int k = 0; k < DD2; ++k) a = fmaf(zp[k], W_ed1[(DD2 + k)*HH + tt], a);
      Zb[b*HH + tt] = a;
    }
    if (t < 2) {
      float a = b_en2[t];
      for (int k = 0; k < HH; ++k) a = fmaf(he[k], W_en2[k*2 + t], a);
      out_en[b*2 + t] = a;
    }
    if (t >= 32 && t < 41) {
      int c = t - 32;
      float a = b_st2[c];
      for (int k = 0; k < HH; ++k) a = fmaf(hs[k], W_st2[k*9 + c], a);
      out_st[b*9 + c] = a;
    }
  } else if (b < BB + 128) {           // W_nep (1024x256) -> Bp, kb = K-octet
    int kb = b - BB;                   // 0..127
    int col = t;
    bf16x8 v;
    #pragma unroll
    for (int j = 0; j < 8; ++j)
      v[j] = (__bf16)W_nep[(kb*8 + j)*256 + col];
    *(bf16x8*)(Bp + (kb*256 + col)*8) = v;
  } else {                             // W_nd1 (256x128) -> Bp2
    int kb = (b - BB - 128)*2 + (t >> 7);   // 0..31
    int col = t & 127;
    bf16x8 v;
    #pragma unroll
    for (int j = 0; j < 8; ++j)
      v[j] = (__bf16)W_nd1[(kb*8 + j)*128 + col];
    *(bf16x8*)(Bp2 + (kb*128 + col)*8) = v;
  }
}

// K3: R[gs][gd][c] = relu(Zt[gs]+Zb[gd]+b_ed1) @ W_ed2 + b_ed2   (256x256x3 table)
__global__ __launch_bounds__(256) void k3_rtab(
    const float* __restrict__ Zt, const float* __restrict__ Zb,
    const float* __restrict__ b_ed1, const float* __restrict__ W_ed2,
    const float* __restrict__ b_ed2, float* __restrict__ R)
{
  int gs = blockIdx.x, gd = threadIdx.x;
  __shared__ float zt_s[HH];
  __shared__ float b1_s[HH];
  __shared__ float w2_s[HH*3];
  if (gd < HH) {
    zt_s[gd] = Zt[gs*HH + gd];
    b1_s[gd] = b_ed1[gd];
    w2_s[gd] = W_ed2[gd];
    w2_s[gd + HH] = W_ed2[gd + HH];
    w2_s[gd + 2*HH] = W_ed2[gd + 2*HH];
  }
  __syncthreads();
  float a0 = b_ed2[0], a1 = b_ed2[1], a2 = b_ed2[2];
  const float* zbrow = Zb + gd*HH;
  #pragma unroll 4
  for (int k = 0; k < HH; ++k) {
    float h = fmaxf(zt_s[k] + zbrow[k] + b1_s[k], 0.f);
    a0 = fmaf(h, w2_s[k*3 + 0], a0);
    a1 = fmaf(h, w2_s[k*3 + 1], a1);
    a2 = fmaf(h, w2_s[k*3 + 2], a2);
  }
  float* o = R + (gs*256 + gd)*3;
  o[0] = a0; o[1] = a1; o[2] = a2;
}

// K4: recon_edge[e] = R[seg[src[e]]][seg[dst[e]]], 4 edges per thread
__global__ __launch_bounds__(256) void k4_edges(
    const int* __restrict__ src, const int* __restrict__ dst,
    const int* __restrict__ seg, const float* __restrict__ R,
    float* __restrict__ out_edge)
{
  int i = blockIdx.x*256 + threadIdx.x;              // 131072 threads
  int4 s4 = ((const int4*)src)[i];
  int4 d4 = ((const int4*)dst)[i];
  int b0 = (seg[s4.x]*256 + seg[d4.x])*3;
  int b1 = (seg[s4.y]*256 + seg[d4.y])*3;
  int b2 = (seg[s4.z]*256 + seg[d4.z])*3;
  int b3 = (seg[s4.w]*256 + seg[d4.w])*3;
  float r00 = R[b0], r01 = R[b0+1], r02 = R[b0+2];
  float r10 = R[b1], r11 = R[b1+1], r12 = R[b1+2];
  float r20 = R[b2], r21 = R[b2+1], r22 = R[b2+2];
  float r30 = R[b3], r31 = R[b3+1], r32 = R[b3+2];
  f32x4* o = (f32x4*)(out_edge + (size_t)i*12);
  f32x4 v0 = { r00, r01, r02, r10 };
  f32x4 v1 = { r11, r12, r20, r21 };
  f32x4 v2 = { r22, r30, r31, r32 };
  o[0] = v0; o[1] = v1; o[2] = v2;
}

// One K-step of GEMM1: consume A regs (2 row-tiles), prefetch A for knext,
// stream 16 B-fragments from L2 and do 32 MFMAs.
__device__ __forceinline__ void k5_step(
    int k, int knext, const float* arow0, const float* arow1,
    const __bf16* Bp, int g4, int l15,
    f32x4& al0, f32x4& ah0, f32x4& al1, f32x4& ah1,
    f32x4 acc0[16], f32x4 acc1[16])
{
  bf16x8 aa0, aa1;
  aa0[0]=(__bf16)al0[0]; aa0[1]=(__bf16)al0[1]; aa0[2]=(__bf16)al0[2]; aa0[3]=(__bf16)al0[3];
  aa0[4]=(__bf16)ah0[0]; aa0[5]=(__bf16)ah0[1]; aa0[6]=(__bf16)ah0[2]; aa0[7]=(__bf16)ah0[3];
  aa1[0]=(__bf16)al1[0]; aa1[1]=(__bf16)al1[1]; aa1[2]=(__bf16)al1[2]; aa1[3]=(__bf16)al1[3];
  aa1[4]=(__bf16)ah1[0]; aa1[5]=(__bf16)ah1[1]; aa1[6]=(__bf16)ah1[2]; aa1[7]=(__bf16)ah1[3];
  int ktA = knext > 31 ? 31 : knext;
  al0 = *(const f32x4*)(arow0 + ktA*32);
  ah0 = *(const f32x4*)(arow0 + ktA*32 + 4);
  al1 = *(const f32x4*)(arow1 + ktA*32);
  ah1 = *(const f32x4*)(arow1 + ktA*32 + 4);
  const bf16x8* bbase = (const bf16x8*)Bp + (size_t)(k*4 + g4)*256 + l15;
  #pragma unroll
  for (int t = 0; t < 16; ++t) {
    bf16x8 bfr = bbase[t*16];
    acc0[t] = __builtin_amdgcn_mfma_f32_16x16x32_bf16(aa0, bfr, acc0[t], 0, 0, 0);
    acc1[t] = __builtin_amdgcn_mfma_f32_16x16x32_bf16(aa1, bfr, acc1[t], 0, 0, 0);
  }
}

// K5: fused node path. 128 rows/block, 4 waves x 32 rows (2 row-tiles each).
// GEMM1 is barrier-free: A streamed HBM->regs (depth-2), B streamed L2->regs.
// nep tile is wave-private in LDS; GEMM2 + heads as before.
__global__ __launch_bounds__(256, 2) void k5_node(
    const float* __restrict__ node_emb, const __bf16* __restrict__ Bp,
    const __bf16* __restrict__ Bp2, const int* __restrict__ seg,
    const float* __restrict__ b_nep, const float* __restrict__ b_nd1,
    const float* __restrict__ W_nd2, const float* __restrict__ b_nd2,
    const float* __restrict__ ZN, float* __restrict__ out_node)
{
  __shared__ __bf16 nep_s[128*264];    // 66 KB, rows wave-private

  const int tid = threadIdx.x;
  const int w = tid >> 6;
  const int l = tid & 63;
  const int l15 = l & 15;
  const int g4 = l >> 4;
  const int wr0 = blockIdx.x*128 + w*32;   // wave's first row

  f32x4 acc[2][16];
  const f32x4 fzero = {0.f, 0.f, 0.f, 0.f};
  #pragma unroll
  for (int rt = 0; rt < 2; ++rt)
    #pragma unroll
    for (int t = 0; t < 16; ++t) acc[rt][t] = fzero;

  const float* arow0 = node_emb + (size_t)(wr0 + l15)*NEF + g4*8;
  const float* arow1 = arow0 + (size_t)16*NEF;

  // depth-2 A prefetch: E set (even steps), O set (odd steps)
  f32x4 aEl0 = *(const f32x4*)(arow0 + 0);
  f32x4 aEh0 = *(const f32x4*)(arow0 + 4);
  f32x4 aEl1 = *(const f32x4*)(arow1 + 0);
  f32x4 aEh1 = *(const f32x4*)(arow1 + 4);
  f32x4 aOl0 = *(const f32x4*)(arow0 + 32);
  f32x4 aOh0 = *(const f32x4*)(arow0 + 36);
  f32x4 aOl1 = *(const f32x4*)(arow1 + 32);
  f32x4 aOh1 = *(const f32x4*)(arow1 + 36);

  for (int kk = 0; kk < 32; kk += 2) {
    k5_step(kk,   kk+2, arow0, arow1, Bp, g4, l15, aEl0, aEh0, aEl1, aEh1, acc[0], acc[1]);
    k5_step(kk+1, kk+3, arow0, arow1, Bp, g4, l15, aOl0, aOh0, aOl1, aOh1, acc[0], acc[1]);
  }

  // epilogue 1: nep = relu(acc + b_nep) -> LDS (bf16), wave-private rows
  #pragma unroll
  for (int rt = 0; rt < 2; ++rt)
    #pragma unroll
    for (int t = 0; t < 16; ++t) {
      int col = t*16 + l15;
      float bn = b_nep[col];
      #pragma unroll
      for (int r = 0; r < 4; ++r) {
        float v = fmaxf(acc[rt][t][r] + bn, 0.f);
        int row = w*32 + rt*16 + g4*4 + r;
        nep_s[row*264 + col] = (__bf16)v;
      }
    }

  // GEMM2: h-pre = nep @ W_nd1 (K=256), cols 0..127 (B fragments from L2)
  f32x4 acc2[2][8];
  #pragma unroll
  for (int rt = 0; rt < 2; ++rt)
    #pragma unroll
    for (int t = 0; t < 8; ++t) acc2[rt][t] = fzero;
  const __bf16* nrow0 = nep_s + (w*32 + l15)*264 + g4*8;
  const __bf16* nrow1 = nrow0 + 16*264;
  #pragma unroll 2
  for (int kk = 0; kk < 8; ++kk) {
    bf16x8 a20 = *(const bf16x8*)(nrow0 + kk*32);
    bf16x8 a21 = *(const bf16x8*)(nrow1 + kk*32);
    #pragma unroll
    for (int t = 0; t < 8; ++t) {
      bf16x8 b2 = *(const bf16x8*)(Bp2 + ((kk*4 + g4)*128 + t*16 + l15)*8);
      acc2[0][t] = __builtin_amdgcn_mfma_f32_16x16x32_bf16(a20, b2, acc2[0][t], 0, 0, 0);
      acc2[1][t] = __builtin_amdgcn_mfma_f32_16x16x32_bf16(a21, b2, acc2[1][t], 0, 0, 0);
    }
  }

  // epilogue 2: h = relu(acc2 + ZN[seg[row]] + b_nd1); recon = h @ W_nd2 + b_nd2
  f32x4 bn2 = *(const f32x4*)b_nd2;
  #pragma unroll
  for (int rt = 0; rt < 2; ++rt) {
    int sid[4];
    #pragma unroll
    for (int r = 0; r < 4; ++r) sid[r] = seg[wr0 + rt*16 + g4*4 + r];
    float p[4][4];
    #pragma unroll
    for (int r = 0; r < 4; ++r)
      #pragma unroll
      for (int c = 0; c < 4; ++c) p[r][c] = 0.f;
    #pragma unroll
    for (int t = 0; t < 8; ++t) {
      int col = t*16 + l15;
      float b1 = b_nd1[col];
      f32x4 w2 = *(const f32x4*)(W_nd2 + col*4);
      #pragma unroll
      for (int r = 0; r < 4; ++r) {
        float h = fmaxf(acc2[rt][t][r] + ZN[sid[r]*HH + col] + b1, 0.f);
        p[r][0] = fmaf(h, w2[0], p[r][0]);
        p[r][1] = fmaf(h, w2[1], p[r][1]);
        p[r][2] = fmaf(h, w2[2], p[r][2]);
        p[r][3] = fmaf(h, w2[3], p[r][3]);
      }
    }
    #pragma unroll
    for (int off = 1; off < 16; off <<= 1)
      #pragma unroll
      for (int r = 0; r < 4; ++r)
        #pragma unroll
        for (int c = 0; c < 4; ++c)
          p[r][c] += __shfl_xor(p[r][c], off, 64);
    if (l15 == 0) {
      #pragma unroll
      for (int r = 0; r < 4; ++r) {
        f32x4 v = { p[r][0] + bn2[0], p[r][1] + bn2[1], p[r][2] + bn2[2], p[r][3] + bn2[3] };
        *(f32x4*)(out_node + (size_t)(wr0 + rt*16 + g4*4 + r)*4) = v;
      }
    }
  }
}

extern "C" void kernel_launch(void* const* d_in, const int* in_sizes, int n_in,
                              void* d_out, int out_size, void* d_ws, size_t ws_size,
                              hipStream_t stream) {
  const float* z        = (const float*)d_in[0];
  const float* node_emb = (const float*)d_in[1];
  const float* lattice  = (const float*)d_in[2];
  const int*   seg      = (const int*)d_in[3];
  const int*   src      = (const int*)d_in[4];
  const int*   dst      = (const int*)d_in[5];
  const float* W_lat    = (const float*)d_in[6];
  const float* b_lat    = (const float*)d_in[7];
  const float* W_nep    = (const float*)d_in[8];
  const float* b_nep    = (const float*)d_in[9];
  const float* W_nd1    = (const float*)d_in[10];
  const float* b_nd1    = (const float*)d_in[11];
  const float* W_nd2    = (const float*)d_in[12];
  const float* b_nd2    = (const float*)d_in[13];
  const float* W_ed1    = (const float*)d_in[14];
  const float* b_ed1    = (const float*)d_in[15];
  const float* W_ed2    = (const float*)d_in[16];
  const float* b_ed2    = (const float*)d_in[17];
  const float* W_en1    = (const float*)d_in[18];
  const float* b_en1    = (const float*)d_in[19];
  const float* W_en2    = (const float*)d_in[20];
  const float* b_en2    = (const float*)d_in[21];
  const float* W_st1    = (const float*)d_in[22];
  const float* b_st1    = (const float*)d_in[23];
  const float* W_st2    = (const float*)d_in[24];
  const float* b_st2    = (const float*)d_in[25];

  char* ws = (char*)d_ws;
  float*  Zt    = (float*)(ws + 0);          // 131072
  float*  Zb    = (float*)(ws + 131072);     // 131072
  float*  ZN    = (float*)(ws + 262144);     // 131072
  float*  Rt    = (float*)(ws + 393216);     // 786432
  __bf16* Bp    = (__bf16*)(ws + 1179648);   // 524288
  __bf16* Bp2   = (__bf16*)(ws + 1703936);   // 65536

  float* out_node = (float*)d_out;                 // 65536*4
  float* out_edge = out_node + 262144;             // 524288*3
  float* out_en   = out_node + 1835008;            // 256*2
  float* out_st   = out_node + 1835520;            // 256*9

  hipLaunchKernelGGL(k1_prep, dim3(400), dim3(256), 0, stream,
                     z, lattice, W_lat, b_lat, W_en1, b_en1, W_en2, b_en2,
                     W_st1, b_st1, W_st2, b_st2, W_nep, W_nd1, W_ed1,
                     Zt, Zb, ZN, Bp, Bp2, out_en, out_st);
  hipLaunchKernelGGL(k3_rtab, dim3(256), dim3(256), 0, stream,
                     Zt, Zb, b_ed1, W_ed2, b_ed2, Rt);
  hipLaunchKernelGGL(k4_edges, dim3(512), dim3(256), 0, stream,
                     src, dst, seg, Rt, out_edge);
  hipLaunchKernelGGL(k5_node, dim3(512), dim3(256), 0, stream,
                     node_emb, Bp, Bp2, seg, b_nep, b_nd1, W_nd2, b_nd2, ZN, out_node);
}

// Round 4
// 120.203 us; speedup vs baseline: 1.4081x; 1.4081x over previous
//
#include <hip/hip_runtime.h>
#include <hip/hip_bf16.h>

#define NN 65536
#define EE 524288
#define BB 256
#define LL 64
#define HH 128
#define DD2 256
#define NEF 1024

typedef __attribute__((ext_vector_type(4))) float f32x4;
typedef __attribute__((ext_vector_type(8))) __bf16 bf16x8;

__device__ __forceinline__ void gload_lds16(const void* g, void* l) {
  __builtin_amdgcn_global_load_lds(
      (__attribute__((address_space(1))) void*)(g),
      (__attribute__((address_space(3))) void*)(l), 16, 0, 0);
}

// K1: fused z-path: z_proj (LDS-only) -> Zt/Zb/ZN rows; energy/stress heads;
// plus weight conversions W_nep->Bp, W_nd1->Bp2 (bf16, fragment-permuted
// [K/8][col][8]) with fully coalesced reads and 16B stores.
__global__ __launch_bounds__(256) void k1_prep(
    const float* __restrict__ z, const float* __restrict__ lattice,
    const float* __restrict__ W_lat, const float* __restrict__ b_lat,
    const float* __restrict__ W_en1, const float* __restrict__ b_en1,
    const float* __restrict__ W_en2, const float* __restrict__ b_en2,
    const float* __restrict__ W_st1, const float* __restrict__ b_st1,
    const float* __restrict__ W_st2, const float* __restrict__ b_st2,
    const float* __restrict__ W_nep, const float* __restrict__ W_nd1,
    const float* __restrict__ W_ed1,
    float* __restrict__ Zt, float* __restrict__ Zb, float* __restrict__ ZN,
    __bf16* __restrict__ Bp, __bf16* __restrict__ Bp2,
    float* __restrict__ out_en, float* __restrict__ out_st)
{
  int b = blockIdx.x, t = threadIdx.x;
  if (b < BB) {
    __shared__ float zl[70];
    __shared__ float zp[DD2];
    __shared__ float he[HH];
    __shared__ float hs[HH];
    if (t < LL) zl[t] = z[b*LL + t];
    else if (t < 70) zl[t] = lattice[t - LL];
    __syncthreads();
    {
      float acc = b_lat[t];
      #pragma unroll 4
      for (int k = 0; k < LL; ++k) acc = fmaf(zl[k], W_lat[k*DD2 + t], acc);
      zp[t] = fmaxf(acc, 0.f);
    }
    if (t < HH) {
      float a = b_en1[t];
      for (int k = 0; k < 70; ++k) a = fmaf(zl[k], W_en1[k*HH + t], a);
      he[t] = fmaxf(a, 0.f);
    } else {
      int tt = t - HH;
      float a = b_st1[tt];
      for (int k = 0; k < 70; ++k) a = fmaf(zl[k], W_st1[k*HH + tt], a);
      hs[tt] = fmaxf(a, 0.f);
    }
    __syncthreads();
    if (t < HH) {
      float a = 0.f, n = 0.f;
      #pragma unroll 4
      for (int k = 0; k < DD2; ++k) {
        a = fmaf(zp[k], W_ed1[k*HH + t], a);
        n = fmaf(zp[k], W_nd1[k*HH + t], n);
      }
      Zt[b*HH + t] = a;
      ZN[b*HH + t] = n;
    } else {
      int tt = t - HH;
      float a = 0.f;
      #pragma unroll 4
      for (int k = 0; k < DD2; ++k) a = fmaf(zp[k], W_ed1[(DD2 + k)*HH + tt], a);
      Zb[b*HH + tt] = a;
    }
    if (t < 2) {
      float a = b_en2[t];
      for (int k = 0; k < HH; ++k) a = fmaf(he[k], W_en2[k*2 + t], a);
      out_en[b*2 + t] = a;
    }
    if (t >= 32 && t < 41) {
      int c = t - 32;
      float a = b_st2[c];
      for (int k = 0; k < HH; ++k) a = fmaf(hs[k], W_st2[k*9 + c], a);
      out_st[b*9 + c] = a;
    }
  } else if (b < BB + 128) {           // W_nep (1024x256) -> Bp, kb = K-octet
    int kb = b - BB;                   // 0..127
    int col = t;
    bf16x8 v;
    #pragma unroll
    for (int j = 0; j < 8; ++j)
      v[j] = (__bf16)W_nep[(kb*8 + j)*256 + col];
    *(bf16x8*)(Bp + (kb*256 + col)*8) = v;
  } else {                             // W_nd1 (256x128) -> Bp2
    int kb = (b - BB - 128)*2 + (t >> 7);   // 0..31
    int col = t & 127;
    bf16x8 v;
    #pragma unroll
    for (int j = 0; j < 8; ++j)
      v[j] = (__bf16)W_nd1[(kb*8 + j)*128 + col];
    *(bf16x8*)(Bp2 + (kb*128 + col)*8) = v;
  }
}

// K3: R[gs][gd][c] = relu(Zt[gs]+Zb[gd]+b_ed1) @ W_ed2 + b_ed2   (256x256x3 table)
__global__ __launch_bounds__(256) void k3_rtab(
    const float* __restrict__ Zt, const float* __restrict__ Zb,
    const float* __restrict__ b_ed1, const float* __restrict__ W_ed2,
    const float* __restrict__ b_ed2, float* __restrict__ R)
{
  int gs = blockIdx.x, gd = threadIdx.x;
  __shared__ float zt_s[HH];
  __shared__ float b1_s[HH];
  __shared__ float w2_s[HH*3];
  if (gd < HH) {
    zt_s[gd] = Zt[gs*HH + gd];
    b1_s[gd] = b_ed1[gd];
    w2_s[gd] = W_ed2[gd];
    w2_s[gd + HH] = W_ed2[gd + HH];
    w2_s[gd + 2*HH] = W_ed2[gd + 2*HH];
  }
  __syncthreads();
  float a0 = b_ed2[0], a1 = b_ed2[1], a2 = b_ed2[2];
  const float* zbrow = Zb + gd*HH;
  #pragma unroll 4
  for (int k = 0; k < HH; ++k) {
    float h = fmaxf(zt_s[k] + zbrow[k] + b1_s[k], 0.f);
    a0 = fmaf(h, w2_s[k*3 + 0], a0);
    a1 = fmaf(h, w2_s[k*3 + 1], a1);
    a2 = fmaf(h, w2_s[k*3 + 2], a2);
  }
  float* o = R + (gs*256 + gd)*3;
  o[0] = a0; o[1] = a1; o[2] = a2;
}

// K4: recon_edge[e] = R[seg[src[e]]][seg[dst[e]]], 4 edges per thread
__global__ __launch_bounds__(256) void k4_edges(
    const int* __restrict__ src, const int* __restrict__ dst,
    const int* __restrict__ seg, const float* __restrict__ R,
    float* __restrict__ out_edge)
{
  int i = blockIdx.x*256 + threadIdx.x;              // 131072 threads
  int4 s4 = ((const int4*)src)[i];
  int4 d4 = ((const int4*)dst)[i];
  int b0 = (seg[s4.x]*256 + seg[d4.x])*3;
  int b1 = (seg[s4.y]*256 + seg[d4.y])*3;
  int b2 = (seg[s4.z]*256 + seg[d4.z])*3;
  int b3 = (seg[s4.w]*256 + seg[d4.w])*3;
  float r00 = R[b0], r01 = R[b0+1], r02 = R[b0+2];
  float r10 = R[b1], r11 = R[b1+1], r12 = R[b1+2];
  float r20 = R[b2], r21 = R[b2+1], r22 = R[b2+2];
  float r30 = R[b3], r31 = R[b3+1], r32 = R[b3+2];
  f32x4* o = (f32x4*)(out_edge + (size_t)i*12);
  f32x4 v0 = { r00, r01, r02, r10 };
  f32x4 v1 = { r11, r12, r20, r21 };
  f32x4 v2 = { r22, r30, r31, r32 };
  o[0] = v0; o[1] = v1; o[2] = v2;
}

// K5: fused node path. 128 rows/block, 4 waves x 32 rows.
// B double-buffered in LDS via global_load_lds; A HBM->regs (E/O sets, 2-iter slack);
// one counted vmcnt(4) + one s_barrier per K-step. Issue order pinned:
// [cvt A(t)] [stage B(t+1)] [load A(t+2)] [ds_read+MFMA] [vmcnt(4)] [barrier]
__global__ __launch_bounds__(256, 2) void k5_node(
    const float* __restrict__ node_emb, const __bf16* __restrict__ Bp,
    const __bf16* __restrict__ Bp2, const int* __restrict__ seg,
    const float* __restrict__ b_nep, const float* __restrict__ b_nd1,
    const float* __restrict__ W_nd2, const float* __restrict__ b_nd2,
    const float* __restrict__ ZN, float* __restrict__ out_node)
{
  // union: B dbuf 2 x 16KB (32KB) / nep tile 128 x 264 bf16 (67584B)
  __shared__ __align__(16) char lds_raw[67584];
  __bf16* Bs    = (__bf16*)lds_raw;
  __bf16* nep_s = (__bf16*)lds_raw;

  const int tid = threadIdx.x;
  const int w = tid >> 6;
  const int l = tid & 63;
  const int l15 = l & 15;
  const int g4 = l >> 4;
  const int wr0 = blockIdx.x*128 + w*32;

  f32x4 acc[2][16];
  const f32x4 fzero = {0.f, 0.f, 0.f, 0.f};
  #pragma unroll
  for (int rt = 0; rt < 2; ++rt)
    #pragma unroll
    for (int t = 0; t < 16; ++t) acc[rt][t] = fzero;

  const float* arow0 = node_emb + (size_t)(wr0 + l15)*NEF + g4*8;
  const float* arow1 = arow0 + (size_t)16*NEF;

  // ---- prologue: stage B(0)->buf0; load A(0)->E, A(1)->O; drain own B(0); barrier
  {
    const __bf16* bsrc = Bp + tid*8;
    #pragma unroll
    for (int i = 0; i < 4; ++i)
      gload_lds16(bsrc + i*2048, Bs + tid*8 + i*2048);
  }
  __builtin_amdgcn_sched_barrier(0);
  f32x4 aEl0 = *(const f32x4*)(arow0 + 0);
  f32x4 aEh0 = *(const f32x4*)(arow0 + 4);
  f32x4 aEl1 = *(const f32x4*)(arow1 + 0);
  f32x4 aEh1 = *(const f32x4*)(arow1 + 4);
  f32x4 aOl0 = *(const f32x4*)(arow0 + 32);
  f32x4 aOh0 = *(const f32x4*)(arow0 + 36);
  f32x4 aOl1 = *(const f32x4*)(arow1 + 32);
  f32x4 aOh1 = *(const f32x4*)(arow1 + 36);
  __builtin_amdgcn_sched_barrier(0);
  asm volatile("s_waitcnt vmcnt(8)" ::: "memory");   // own B(0) staged; A(0),A(1) may fly
  __builtin_amdgcn_s_barrier();
  __builtin_amdgcn_sched_barrier(0);

  #define K5_ITER(T, AL0, AH0, AL1, AH1)                                        \
  {                                                                             \
    bf16x8 aa0, aa1;                                                            \
    aa0[0]=(__bf16)AL0[0]; aa0[1]=(__bf16)AL0[1]; aa0[2]=(__bf16)AL0[2]; aa0[3]=(__bf16)AL0[3]; \
    aa0[4]=(__bf16)AH0[0]; aa0[5]=(__bf16)AH0[1]; aa0[6]=(__bf16)AH0[2]; aa0[7]=(__bf16)AH0[3]; \
    aa1[0]=(__bf16)AL1[0]; aa1[1]=(__bf16)AL1[1]; aa1[2]=(__bf16)AL1[2]; aa1[3]=(__bf16)AL1[3]; \
    aa1[4]=(__bf16)AH1[0]; aa1[5]=(__bf16)AH1[1]; aa1[6]=(__bf16)AH1[2]; aa1[7]=(__bf16)AH1[3]; \
    __builtin_amdgcn_sched_barrier(0);                                          \
    {  /* stage B(T+1) -> buf[(T+1)&1] */                                       \
      const __bf16* bsrc = Bp + (size_t)(((T) + 1) & 31)*8192 + tid*8;          \
      __bf16* bdst = Bs + (((T) + 1) & 1)*8192 + tid*8;                         \
      _Pragma("unroll")                                                         \
      for (int i = 0; i < 4; ++i)                                               \
        gload_lds16(bsrc + i*2048, bdst + i*2048);                              \
    }                                                                           \
    __builtin_amdgcn_sched_barrier(0);                                          \
    {  /* load A(T+2) back into this set */                                     \
      int kA = (T) + 2 > 31 ? 31 : (T) + 2;                                     \
      AL0 = *(const f32x4*)(arow0 + kA*32);                                     \
      AH0 = *(const f32x4*)(arow0 + kA*32 + 4);                                 \
      AL1 = *(const f32x4*)(arow1 + kA*32);                                     \
      AH1 = *(const f32x4*)(arow1 + kA*32 + 4);                                 \
    }                                                                           \
    __builtin_amdgcn_sched_barrier(0);                                          \
    {  /* consume tile T from buf[T&1] */                                       \
      const bf16x8* Bv = (const bf16x8*)(Bs + ((T) & 1)*8192);                  \
      _Pragma("unroll")                                                         \
      for (int tt = 0; tt < 16; ++tt) {                                         \
        bf16x8 bfr = Bv[g4*256 + tt*16 + l15];                                  \
        acc[0][tt] = __builtin_amdgcn_mfma_f32_16x16x32_bf16(aa0, bfr, acc[0][tt], 0, 0, 0); \
        acc[1][tt] = __builtin_amdgcn_mfma_f32_16x16x32_bf16(aa1, bfr, acc[1][tt], 0, 0, 0); \
      }                                                                         \
    }                                                                           \
    __builtin_amdgcn_sched_barrier(0);                                          \
    asm volatile("s_waitcnt vmcnt(4)" ::: "memory");                            \
    __builtin_amdgcn_s_barrier();                                               \
    __builtin_amdgcn_sched_barrier(0);                                          \
  }

  for (int kk = 0; kk < 32; kk += 2) {
    K5_ITER(kk,     aEl0, aEh0, aEl1, aEh1);
    K5_ITER(kk + 1, aOl0, aOh0, aOl1, aOh1);
  }
  #undef K5_ITER

  // drain trailing stage + A loads before nep_s overwrites the union
  asm volatile("s_waitcnt vmcnt(0)" ::: "memory");
  __syncthreads();

  // epilogue 1: nep = relu(acc + b_nep) -> LDS (bf16), wave-private rows
  #pragma unroll
  for (int rt = 0; rt < 2; ++rt)
    #pragma unroll
    for (int t = 0; t < 16; ++t) {
      int col = t*16 + l15;
      float bn = b_nep[col];
      #pragma unroll
      for (int r = 0; r < 4; ++r) {
        float v = fmaxf(acc[rt][t][r] + bn, 0.f);
        int row = w*32 + rt*16 + g4*4 + r;
        nep_s[row*264 + col] = (__bf16)v;
      }
    }

  // GEMM2: h-pre = nep @ W_nd1 (K=256), cols 0..127 (B fragments from L2)
  f32x4 acc2[2][8];
  #pragma unroll
  for (int rt = 0; rt < 2; ++rt)
    #pragma unroll
    for (int t = 0; t < 8; ++t) acc2[rt][t] = fzero;
  const __bf16* nrow0 = nep_s + (w*32 + l15)*264 + g4*8;
  const __bf16* nrow1 = nrow0 + 16*264;
  #pragma unroll 2
  for (int kk = 0; kk < 8; ++kk) {
    bf16x8 a20 = *(const bf16x8*)(nrow0 + kk*32);
    bf16x8 a21 = *(const bf16x8*)(nrow1 + kk*32);
    #pragma unroll
    for (int t = 0; t < 8; ++t) {
      bf16x8 b2 = *(const bf16x8*)(Bp2 + ((kk*4 + g4)*128 + t*16 + l15)*8);
      acc2[0][t] = __builtin_amdgcn_mfma_f32_16x16x32_bf16(a20, b2, acc2[0][t], 0, 0, 0);
      acc2[1][t] = __builtin_amdgcn_mfma_f32_16x16x32_bf16(a21, b2, acc2[1][t], 0, 0, 0);
    }
  }

  // epilogue 2: h = relu(acc2 + ZN[seg[row]] + b_nd1); recon = h @ W_nd2 + b_nd2
  f32x4 bn2 = *(const f32x4*)b_nd2;
  #pragma unroll
  for (int rt = 0; rt < 2; ++rt) {
    int sid[4];
    #pragma unroll
    for (int r = 0; r < 4; ++r) sid[r] = seg[wr0 + rt*16 + g4*4 + r];
    float p[4][4];
    #pragma unroll
    for (int r = 0; r < 4; ++r)
      #pragma unroll
      for (int c = 0; c < 4; ++c) p[r][c] = 0.f;
    #pragma unroll
    for (int t = 0; t < 8; ++t) {
      int col = t*16 + l15;
      float b1 = b_nd1[col];
      f32x4 w2 = *(const f32x4*)(W_nd2 + col*4);
      #pragma unroll
      for (int r = 0; r < 4; ++r) {
        float h = fmaxf(acc2[rt][t][r] + ZN[sid[r]*HH + col] + b1, 0.f);
        p[r][0] = fmaf(h, w2[0], p[r][0]);
        p[r][1] = fmaf(h, w2[1], p[r][1]);
        p[r][2] = fmaf(h, w2[2], p[r][2]);
        p[r][3] = fmaf(h, w2[3], p[r][3]);
      }
    }
    #pragma unroll
    for (int off = 1; off < 16; off <<= 1)
      #pragma unroll
      for (int r = 0; r < 4; ++r)
        #pragma unroll
        for (int c = 0; c < 4; ++c)
          p[r][c] += __shfl_xor(p[r][c], off, 64);
    if (l15 == 0) {
      #pragma unroll
      for (int r = 0; r < 4; ++r) {
        f32x4 v = { p[r][0] + bn2[0], p[r][1] + bn2[1], p[r][2] + bn2[2], p[r][3] + bn2[3] };
        *(f32x4*)(out_node + (size_t)(wr0 + rt*16 + g4*4 + r)*4) = v;
      }
    }
  }
}

extern "C" void kernel_launch(void* const* d_in, const int* in_sizes, int n_in,
                              void* d_out, int out_size, void* d_ws, size_t ws_size,
                              hipStream_t stream) {
  const float* z        = (const float*)d_in[0];
  const float* node_emb = (const float*)d_in[1];
  const float* lattice  = (const float*)d_in[2];
  const int*   seg      = (const int*)d_in[3];
  const int*   src      = (const int*)d_in[4];
  const int*   dst      = (const int*)d_in[5];
  const float* W_lat    = (const float*)d_in[6];
  const float* b_lat    = (const float*)d_in[7];
  const float* W_nep    = (const float*)d_in[8];
  const float* b_nep    = (const float*)d_in[9];
  const float* W_nd1    = (const float*)d_in[10];
  const float* b_nd1    = (const float*)d_in[11];
  const float* W_nd2    = (const float*)d_in[12];
  const float* b_nd2    = (const float*)d_in[13];
  const float* W_ed1    = (const float*)d_in[14];
  const float* b_ed1    = (const float*)d_in[15];
  const float* W_ed2    = (const float*)d_in[16];
  const float* b_ed2    = (const float*)d_in[17];
  const float* W_en1    = (const float*)d_in[18];
  const float* b_en1    = (const float*)d_in[19];
  const float* W_en2    = (const float*)d_in[20];
  const float* b_en2    = (const float*)d_in[21];
  const float* W_st1    = (const float*)d_in[22];
  const float* b_st1    = (const float*)d_in[23];
  const float* W_st2    = (const float*)d_in[24];
  const float* b_st2    = (const float*)d_in[25];

  char* ws = (char*)d_ws;
  float*  Zt    = (float*)(ws + 0);          // 131072
  float*  Zb    = (float*)(ws + 131072);     // 131072
  float*  ZN    = (float*)(ws + 262144);     // 131072
  float*  Rt    = (float*)(ws + 393216);     // 786432
  __bf16* Bp    = (__bf16*)(ws + 1179648);   // 524288
  __bf16* Bp2   = (__bf16*)(ws + 1703936);   // 65536

  float* out_node = (float*)d_out;                 // 65536*4
  float* out_edge = out_node + 262144;             // 524288*3
  float* out_en   = out_node + 1835008;            // 256*2
  float* out_st   = out_node + 1835520;            // 256*9

  hipLaunchKernelGGL(k1_prep, dim3(400), dim3(256), 0, stream,
                     z, lattice, W_lat, b_lat, W_en1, b_en1, W_en2, b_en2,
                     W_st1, b_st1, W_st2, b_st2, W_nep, W_nd1, W_ed1,
                     Zt, Zb, ZN, Bp, Bp2, out_en, out_st);
  hipLaunchKernelGGL(k3_rtab, dim3(256), dim3(256), 0, stream,
                     Zt, Zb, b_ed1, W_ed2, b_ed2, Rt);
  hipLaunchKernelGGL(k4_edges, dim3(512), dim3(256), 0, stream,
                     src, dst, seg, Rt, out_edge);
  hipLaunchKernelGGL(k5_node, dim3(512), dim3(256), 0, stream,
                     node_emb, Bp, Bp2, seg, b_nep, b_nd1, W_nd2, b_nd2, ZN, out_node);
}